// Round 8
// baseline (403.988 us; speedup 1.0000x reference)
//
#include <hip/hip_runtime.h>
#include <math.h>

#define NB     16      // batches
#define NP     4096    // points per cloud (N == M)
#define BLK    1024    // 16 waves
#define NWAVE  16
#define ILP    8       // x-points per lane
#define XPB    (64 * ILP)     // 512 x-points per block (every wave holds all)
#define YHALF  (NP / 2)       // 2048 y per block, staged ONCE (32 KB LDS)
#define NPAIR  (YHALF / 2)    // 1024 y-pairs
#define PQ     (NPAIR / NWAVE) // 64 pairs per wave

typedef float f32x2 __attribute__((ext_vector_type(2)));

// R7 post-mortem: issue-slot-bound at ~1.04 VALU instr/cyc/CU (practical
// ceiling ~1.3, m07). Fix: packed fp32. Y-pairs in LDS as (x0,x1,y0,y1) +
// (z0,z1,-.5|y0|^2,-.5|y1|^2); inner update = 3 v_pk_fma_f32 + 1 v_max3_f32
// = 2.0 slots/pair (was 3.5). Single 32KB stage, no chunk loop/barriers.
// d/2 = 0.5||x||^2 - m, min-d == max-m; subtract/clamp in epilogue; y-halves
// combine across blocks via uint atomicMin (valid: clamped e >= 0).
__global__ __launch_bounds__(BLK, 8) void chamfer_kernel(
    const float* __restrict__ A1, const float* __restrict__ A2,
    unsigned int* __restrict__ minbits)
{
    __shared__ float4 s0[NPAIR];   // (x0,x1,y0,y1)
    __shared__ float4 s1[NPAIR];   // (z0,z1,w0,w1)
    const int b   = blockIdx.x;    // batch
    const int xc  = blockIdx.y;    // x-chunk (NP/XPB = 8)
    const int z   = blockIdx.z;    // bit0: y-half, bit1: direction
    const int yh  = z & 1;
    const int dir = z >> 1;
    const float* X = dir ? A2 : A1;
    const float* Y = dir ? A1 : A2;

    const int tid  = threadIdx.x;
    const int lane = tid & 63;
    const int w    = tid >> 6;     // 0..15

    // Stage this y-half: thread i packs y-pair (2i, 2i+1). 24 B/lane contiguous.
    {
        const float* yp = Y + ((size_t)b * NP + yh * YHALF + 2 * tid) * 3;
        const float x0 = yp[0], y0 = yp[1], z0 = yp[2];
        const float x1 = yp[3], y1 = yp[4], z1 = yp[5];
        s0[tid] = make_float4(x0, x1, y0, y1);
        s1[tid] = make_float4(z0, z1,
                              -0.5f * (x0 * x0 + y0 * y0 + z0 * z0),
                              -0.5f * (x1 * x1 + y1 * y1 + z1 * z1));
    }

    // My 8 x-points (lanes contiguous within each p -> coalesced 12 B/lane).
    const float* Xb = X + ((size_t)b * NP + xc * XPB) * 3;
    float px[ILP], py[ILP], pz[ILP], ax[ILP], mx[ILP];
    #pragma unroll
    for (int p = 0; p < ILP; ++p) {
        const int n = p * 64 + lane;
        px[p] = Xb[n * 3 + 0];
        py[p] = Xb[n * 3 + 1];
        pz[p] = Xb[n * 3 + 2];
        ax[p] = 0.5f * (px[p] * px[p] + py[p] * py[p] + pz[p] * pz[p]);
        mx[p] = -3.3e38f;
    }
    __syncthreads();

    const float4* s0q = s0 + w * PQ;   // this wave's 64 pairs
    const float4* s1q = s1 + w * PQ;
    #pragma unroll 2
    for (int j = 0; j < PQ; ++j) {
        const float4 a = s0q[j];       // broadcast ds_read_b128
        const float4 c = s1q[j];
        const f32x2 X2 = {a.x, a.y}, Y2 = {a.z, a.w};
        const f32x2 Z2 = {c.x, c.y}, W2 = {c.z, c.w};
        #pragma unroll
        for (int p = 0; p < ILP; ++p) {
            f32x2 pz2 = {pz[p], pz[p]};
            f32x2 py2 = {py[p], py[p]};
            f32x2 px2 = {px[p], px[p]};
            f32x2 m = __builtin_elementwise_fma(pz2, Z2, W2);   // v_pk_fma_f32
            m = __builtin_elementwise_fma(py2, Y2, m);
            m = __builtin_elementwise_fma(px2, X2, m);
            mx[p] = fmaxf(mx[p], fmaxf(m.x, m.y));              // v_max3_f32
        }
    }

    // Tree-combine 16 wave-partials (reusing s0/s1 LDS), then atomicMin per x.
    __syncthreads();
    float* sbuf = (float*)s0;
    for (int half = NWAVE / 2; half >= 1; half >>= 1) {
        if (w >= half && w < 2 * half) {
            #pragma unroll
            for (int p = 0; p < ILP; ++p)
                sbuf[(w - half) * XPB + p * 64 + lane] = mx[p];
        }
        __syncthreads();
        if (w < half) {
            #pragma unroll
            for (int p = 0; p < ILP; ++p)
                mx[p] = fmaxf(mx[p], sbuf[w * XPB + p * 64 + lane]);
        }
        __syncthreads();
    }

    if (w == 0) {   // wave 0 holds the block max over this y-half
        unsigned int* mb = minbits + ((size_t)dir * NB + b) * NP + xc * XPB;
        #pragma unroll
        for (int p = 0; p < ILP; ++p) {
            const float e = fmaxf(ax[p] - mx[p], 0.0f);   // = d_min/2 (this half)
            atomicMin(&mb[p * 64 + lane], __float_as_uint(e));  // coalesced
        }
    }
}

// 32 blocks x 1024: one uint4 per thread, sqrt(2e), reduce, atomicAdd.
__global__ __launch_bounds__(1024) void reduce_kernel(
    const unsigned int* __restrict__ minbits, float* __restrict__ out)
{
    const uint4 u = ((const uint4*)minbits)[blockIdx.x * 1024 + threadIdx.x];
    float s = sqrtf(2.0f * __uint_as_float(u.x)) + sqrtf(2.0f * __uint_as_float(u.y))
            + sqrtf(2.0f * __uint_as_float(u.z)) + sqrtf(2.0f * __uint_as_float(u.w));
    #pragma unroll
    for (int off = 32; off > 0; off >>= 1)
        s += __shfl_down(s, off, 64);

    __shared__ float ws[16];
    const int lane = threadIdx.x & 63;
    const int wid  = threadIdx.x >> 6;
    if (lane == 0) ws[wid] = s;
    __syncthreads();
    if (threadIdx.x == 0) {
        float t = 0.0f;
        #pragma unroll
        for (int v = 0; v < 16; ++v) t += ws[v];
        // out = (sum1+sum2) * 1000 / (2 * NB * NP); 1000/131072 exact in fp32.
        atomicAdd(out, t * 0.00762939453125f);
    }
}

extern "C" void kernel_launch(void* const* d_in, const int* in_sizes, int n_in,
                              void* d_out, int out_size, void* d_ws, size_t ws_size,
                              hipStream_t stream)
{
    const float* a1 = (const float*)d_in[0];  // [NB, NP, 3] fp32
    const float* a2 = (const float*)d_in[1];  // [NB, NP, 3] fp32
    float* out = (float*)d_out;
    unsigned int* minbits = (unsigned int*)d_ws;   // [2, NB, NP]

    // 0x7F7F7F7F ~ 3.39e38f > any clamped e; uint order == float order (e>=0).
    hipMemsetAsync(minbits, 0x7F, (size_t)2 * NB * NP * sizeof(unsigned int), stream);
    hipMemsetAsync(out, 0, sizeof(float), stream);

    dim3 grid(NB, NP / XPB, 4);   // 16 x 8 x (2 y-half * 2 dir) = 512 blocks = 2/CU
    chamfer_kernel<<<grid, BLK, 0, stream>>>(a1, a2, minbits);

    reduce_kernel<<<(2 * NB * NP) / 4096, 1024, 0, stream>>>(minbits, out);
}

// Round 9
// 110.651 us; speedup vs baseline: 3.6510x; 3.6510x over previous
//
#include <hip/hip_runtime.h>
#include <math.h>

#define NB     16      // batches
#define NP     4096    // points per cloud (N == M)
#define BLK    256     // 4 waves per block
#define NWAVE  4
#define ILP    8       // x-points per lane
#define XPB    (64 * ILP)      // 512 x-points per block (every wave holds all)
#define YQUART (NP / 4)        // 1024 y per block, staged once (16 KB LDS)
#define NPAIR  (YQUART / 2)    // 512 y-pairs
#define PQ     (NPAIR / NWAVE) // 128 pairs per wave

typedef float f32x2 __attribute__((ext_vector_type(2)));

// R8 post-mortem: __builtin_elementwise_fma lowered through scratch (738MB
// fetch + 707MB write spill signature). Packed math is now forced via inline
// asm v_pk_fma_f32; x broadcast pairs {v,v} are loop-invariant registers, so
// no op_sel needed. Inner update per (1x, 2y): 3 pk_fma + 1 max3 = 2.0
// slots/pair (R7: 3.5). Y staged once per block (quarter, 16 KB) -> no mid
// -kernel barriers; 4 blocks/CU. Partials stored unconditionally as floats
// (full coverage -> no workspace memset node); reduce mins the 4 quarters.
__global__ __launch_bounds__(BLK, 4) void chamfer_kernel(
    const float* __restrict__ A1, const float* __restrict__ A2,
    float* __restrict__ part)
{
    __shared__ float4 s0[NPAIR];   // (x0,x1,y0,y1)
    __shared__ float4 s1[NPAIR];   // (z0,z1,w0,w1), w = -0.5*||y||^2
    const int b   = blockIdx.x;    // batch
    const int xc  = blockIdx.y;    // x-chunk (NP/XPB = 8)
    const int z   = blockIdx.z;    // bits 0..1: y-quarter, bit 2: direction
    const int yq  = z & 3;
    const int dir = z >> 2;
    const float* X = dir ? A2 : A1;
    const float* Y = dir ? A1 : A2;

    const int tid  = threadIdx.x;
    const int lane = tid & 63;
    const int w    = tid >> 6;     // 0..3

    // Stage this y-quarter: thread t packs pairs t and t+256 (24 B each).
    {
        const float* Yq = Y + ((size_t)b * NP + yq * YQUART) * 3;
        for (int i = tid; i < NPAIR; i += BLK) {
            const float* yp = Yq + 6 * i;
            const float x0 = yp[0], y0 = yp[1], z0 = yp[2];
            const float x1 = yp[3], y1 = yp[4], z1 = yp[5];
            s0[i] = make_float4(x0, x1, y0, y1);
            s1[i] = make_float4(z0, z1,
                                -0.5f * (x0 * x0 + y0 * y0 + z0 * z0),
                                -0.5f * (x1 * x1 + y1 * y1 + z1 * z1));
        }
    }

    // My 8 x-points as broadcast pairs (loop-invariant registers).
    const float* Xb = X + ((size_t)b * NP + xc * XPB) * 3;
    f32x2 px2[ILP], py2[ILP], pz2[ILP];
    float ax[ILP], mx[ILP];
    #pragma unroll
    for (int p = 0; p < ILP; ++p) {
        const int n = p * 64 + lane;
        const float x = Xb[n * 3 + 0], y = Xb[n * 3 + 1], zz = Xb[n * 3 + 2];
        px2[p] = (f32x2){x, x};
        py2[p] = (f32x2){y, y};
        pz2[p] = (f32x2){zz, zz};
        ax[p] = 0.5f * (x * x + y * y + zz * zz);
        mx[p] = -3.3e38f;
    }
    __syncthreads();

    const float4* s0q = s0 + w * PQ;   // this wave's 128 pairs
    const float4* s1q = s1 + w * PQ;
    #pragma unroll 2
    for (int j = 0; j < PQ; ++j) {
        const float4 a = s0q[j];       // broadcast ds_read_b128
        const float4 c = s1q[j];
        const f32x2 X2 = {a.x, a.y}, Y2 = {a.z, a.w};
        const f32x2 Z2 = {c.x, c.y}, W2 = {c.z, c.w};
        #pragma unroll
        for (int p = 0; p < ILP; ++p) {
            f32x2 m;
            asm("v_pk_fma_f32 %0, %1, %2, %3"
                : "=v"(m) : "v"(pz2[p]), "v"(Z2), "v"(W2));
            asm("v_pk_fma_f32 %0, %1, %2, %0"
                : "+v"(m) : "v"(py2[p]), "v"(Y2));
            asm("v_pk_fma_f32 %0, %1, %2, %0"
                : "+v"(m) : "v"(px2[p]), "v"(X2));
            mx[p] = fmaxf(mx[p], fmaxf(m.x, m.y));   // v_max3_f32
        }
    }

    // Tree-combine the 4 wave-partials (reuse s0 as float buffer).
    __syncthreads();
    float* sbuf = (float*)s0;
    for (int half = NWAVE / 2; half >= 1; half >>= 1) {
        if (w >= half && w < 2 * half) {
            #pragma unroll
            for (int p = 0; p < ILP; ++p)
                sbuf[(w - half) * XPB + p * 64 + lane] = mx[p];
        }
        __syncthreads();
        if (w < half) {
            #pragma unroll
            for (int p = 0; p < ILP; ++p)
                mx[p] = fmaxf(mx[p], sbuf[w * XPB + p * 64 + lane]);
        }
        __syncthreads();
    }

    if (w == 0) {   // block max over this y-quarter -> plain coalesced store
        float* pb = part + ((size_t)(yq * 2 * NB + dir * NB + b)) * NP + xc * XPB;
        #pragma unroll
        for (int p = 0; p < ILP; ++p)
            pb[p * 64 + lane] = fmaxf(ax[p] - mx[p], 0.0f);   // = d_min/2 (quarter)
    }
}

// 32 blocks x 1024: each thread 4 x-slots; min over the 4 y-quarters,
// sqrt(2e), block reduce, one atomicAdd.
__global__ __launch_bounds__(1024) void reduce_kernel(
    const float* __restrict__ part, float* __restrict__ out)
{
    const int S = 2 * NB * NP;   // 131072 x-slots per quarter
    float s = 0.0f;
    #pragma unroll
    for (int k = 0; k < 4; ++k) {
        const int slot = blockIdx.x * 1024 + threadIdx.x + k * 32768;
        const float e = fminf(fminf(part[slot], part[S + slot]),
                              fminf(part[2 * S + slot], part[3 * S + slot]));
        s += sqrtf(2.0f * e);
    }
    #pragma unroll
    for (int off = 32; off > 0; off >>= 1)
        s += __shfl_down(s, off, 64);

    __shared__ float ws[16];
    const int lane = threadIdx.x & 63;
    const int wid  = threadIdx.x >> 6;
    if (lane == 0) ws[wid] = s;
    __syncthreads();
    if (threadIdx.x == 0) {
        float t = 0.0f;
        #pragma unroll
        for (int v = 0; v < 16; ++v) t += ws[v];
        // out = (sum1+sum2) * 1000 / (2 * NB * NP); 1000/131072 exact in fp32.
        atomicAdd(out, t * 0.00762939453125f);
    }
}

extern "C" void kernel_launch(void* const* d_in, const int* in_sizes, int n_in,
                              void* d_out, int out_size, void* d_ws, size_t ws_size,
                              hipStream_t stream)
{
    const float* a1 = (const float*)d_in[0];  // [NB, NP, 3] fp32
    const float* a2 = (const float*)d_in[1];  // [NB, NP, 3] fp32
    float* out = (float*)d_out;
    float* part = (float*)d_ws;   // [4 quarters][2 dir][NB][NP] floats = 2 MB

    hipMemsetAsync(out, 0, sizeof(float), stream);   // d_out poisoned 0xAA

    dim3 grid(NB, NP / XPB, 8);   // 16 x 8 x (4 quarters * 2 dir) = 1024 = 4/CU
    chamfer_kernel<<<grid, BLK, 0, stream>>>(a1, a2, part);

    reduce_kernel<<<32, 1024, 0, stream>>>(part, out);
}

// Round 10
// 93.040 us; speedup vs baseline: 4.3421x; 1.1893x over previous
//
#include <hip/hip_runtime.h>
#include <math.h>

#define NB    16
#define NP    4096
#define CLOUD (NB * NP)        // 65536 points per cloud
#define XT    8                // x-tiles (16 rows each) per wave -> 128 x
#define YSPL  4                // y splits (occupancy: 4096 waves = 4/SIMD)
#define YPS   (NP / YSPL)      // 1024 y per split
#define YT    (YPS / 16)       // 64 y-tiles per split

typedef _Float16 f16;
typedef _Float16 f16x4 __attribute__((ext_vector_type(4)));
typedef _Float16 f16x8 __attribute__((ext_vector_type(8)));
typedef float    f32x4v __attribute__((ext_vector_type(4)));

// R9 post-mortem: fp32 vector floor is ~24us regardless of pk packing (pk_fma
// = 4cyc/instr, same FLOP rate). Escape: K=3 GEMM on f16 MFMA (2.5PF pipe).
// m = dot(x^,y^) - 0.5||y^||^2 via bias-in-C; e = 0.5||x^||^2 - max m =
// 0.5||x^-y^||^2 >= 0 exactly (biases from ROUNDED coords). Zero-padding all
// k>2 slots makes the result independent of A/B fragment k-layout details.

// Pre-pass: round to f16 quads + per-point 0.5||p^||^2 (fp32, from rounded).
__global__ __launch_bounds__(256) void prep_kernel(
    const float* __restrict__ A1, const float* __restrict__ A2,
    f16x4* __restrict__ h4, float* __restrict__ aa)
{
    const int i = blockIdx.x * 256 + threadIdx.x;     // 0 .. 2*CLOUD
    const int off = (i < CLOUD) ? i : i - CLOUD;
    const float* p = ((i < CLOUD) ? A1 : A2) + (size_t)off * 3;
    const f16 hx = (f16)p[0], hy = (f16)p[1], hz = (f16)p[2];
    h4[i] = (f16x4){hx, hy, hz, (f16)0.f};
    const float fx = (float)hx, fy = (float)hy, fz = (float)hz;
    aa[i] = 0.5f * (fx * fx + fy * fy + fz * fz);
}

// Each wave: 8 x-tiles (128 x-rows) vs one y-split (1024 y), no LDS (12 KB
// y-split working set is L1-resident), no barriers. C/D: col=lane&15,
// row=(lane>>4)*4+reg (m89). A/B frags: data in lane-group 0, elems 0..2
// (k=0,1,2); all other slots zero -> layout-robust.
__global__ __launch_bounds__(256, 4) void mfma_kernel(
    const f16x4* __restrict__ h4, const float* __restrict__ aa,
    float* __restrict__ part)
{
    const int b  = blockIdx.x;
    const int xs = blockIdx.y;          // x-super: 512 rows
    const int z  = blockIdx.z;
    const int yq = z & 3, dir = z >> 2;

    const int tid = threadIdx.x, lane = tid & 63, w = tid >> 6;
    const int c = lane & 15;            // col (B/C) / row-within-tile (A)
    const int g = lane >> 4;            // k-slice group
    const bool lo = (g == 0);

    const f16x4* hX = h4 + (size_t)dir * CLOUD + (size_t)b * NP;
    const f16x4* hY = h4 + (size_t)(dir ^ 1) * CLOUD + (size_t)b * NP + yq * YPS;
    const float* aY = aa + (size_t)(dir ^ 1) * CLOUD + (size_t)b * NP + yq * YPS;

    const int xbase = xs * 512 + w * 128;

    // A-fragments: row c of each x-tile, k=0..2 = (x,y,z), rest zero.
    f16x8 afrag[XT];
    #pragma unroll
    for (int t = 0; t < XT; ++t) {
        const f16x4 q = hX[xbase + t * 16 + c];
        f16x8 af = (f16x8){q.x, q.y, q.z, (f16)0.f,
                           (f16)0.f, (f16)0.f, (f16)0.f, (f16)0.f};
        if (!lo) af = (f16x8)(f16)0.f;   // zero k-slices of lane groups 1..3
        afrag[t] = af;
    }

    float mx[XT][4];
    #pragma unroll
    for (int t = 0; t < XT; ++t) {
        #pragma unroll
        for (int r = 0; r < 4; ++r) mx[t][r] = -3.3e38f;
    }

    for (int j = 0; j < YT; j += 2) {   // two y-tiles per iter -> v_max3 fuse
        const f16x4 q0 = hY[j * 16 + c];
        const f16x4 q1 = hY[j * 16 + 16 + c];
        const float av0 = aY[j * 16 + c];
        const float av1 = aY[j * 16 + 16 + c];
        f16x8 bf0 = (f16x8){q0.x, q0.y, q0.z, (f16)0.f,
                            (f16)0.f, (f16)0.f, (f16)0.f, (f16)0.f};
        f16x8 bf1 = (f16x8){q1.x, q1.y, q1.z, (f16)0.f,
                            (f16)0.f, (f16)0.f, (f16)0.f, (f16)0.f};
        if (!lo) { bf0 = (f16x8)(f16)0.f; bf1 = (f16x8)(f16)0.f; }
        const float bv0 = -av0, bv1 = -av1;
        const f32x4v c0 = {bv0, bv0, bv0, bv0};   // bias per col (lane's col)
        const f32x4v c1 = {bv1, bv1, bv1, bv1};
        #pragma unroll
        for (int t = 0; t < XT; ++t) {
            const f32x4v d0 =
                __builtin_amdgcn_mfma_f32_16x16x32_f16(afrag[t], bf0, c0, 0, 0, 0);
            const f32x4v d1 =
                __builtin_amdgcn_mfma_f32_16x16x32_f16(afrag[t], bf1, c1, 0, 0, 0);
            #pragma unroll
            for (int r = 0; r < 4; ++r)
                mx[t][r] = fmaxf(fmaxf(mx[t][r], d0[r]), d1[r]);  // v_max3_f32
        }
    }

    // Cross-lane max over the 16 cols (lane bits 0..3), then one store per x.
    float* pslice = part + (size_t)yq * (2 * CLOUD)
                  + (size_t)dir * CLOUD + (size_t)b * NP;
    #pragma unroll
    for (int t = 0; t < XT; ++t) {
        #pragma unroll
        for (int r = 0; r < 4; ++r) {
            float v = mx[t][r];
            v = fmaxf(v, __shfl_xor(v, 1, 64));
            v = fmaxf(v, __shfl_xor(v, 2, 64));
            v = fmaxf(v, __shfl_xor(v, 4, 64));
            v = fmaxf(v, __shfl_xor(v, 8, 64));
            if (c == 0)
                pslice[xbase + t * 16 + g * 4 + r] = v;   // row = t*16+g*4+r
        }
    }
}

// 128 blocks x 1024: max over 4 y-splits, e = a - m (>=0), sqrt(2e), sum.
__global__ __launch_bounds__(1024) void reduce_kernel(
    const float* __restrict__ part, const float* __restrict__ aa,
    float* __restrict__ out)
{
    const int i = blockIdx.x * 1024 + threadIdx.x;   // dir*CLOUD + b*NP + x
    const int S = 2 * CLOUD;
    const float m = fmaxf(fmaxf(part[i], part[S + i]),
                          fmaxf(part[2 * S + i], part[3 * S + i]));
    const float e = fmaxf(aa[i] - m, 0.0f);          // = d_min / 2
    float s = sqrtf(2.0f * e);
    #pragma unroll
    for (int off = 32; off > 0; off >>= 1)
        s += __shfl_down(s, off, 64);

    __shared__ float ws[16];
    const int lane = threadIdx.x & 63;
    const int wid  = threadIdx.x >> 6;
    if (lane == 0) ws[wid] = s;
    __syncthreads();
    if (threadIdx.x == 0) {
        float t = 0.0f;
        #pragma unroll
        for (int v = 0; v < 16; ++v) t += ws[v];
        // out = (sum1+sum2) * 1000 / (2 * NB * NP); 1000/131072 exact in fp32.
        atomicAdd(out, t * 0.00762939453125f);
    }
}

extern "C" void kernel_launch(void* const* d_in, const int* in_sizes, int n_in,
                              void* d_out, int out_size, void* d_ws, size_t ws_size,
                              hipStream_t stream)
{
    const float* a1 = (const float*)d_in[0];  // [NB, NP, 3] fp32
    const float* a2 = (const float*)d_in[1];  // [NB, NP, 3] fp32
    float* out = (float*)d_out;

    // ws: h4 (1 MiB) | aa (0.5 MiB) | part (2 MiB)
    f16x4* h4 = (f16x4*)d_ws;
    float* aa = (float*)((char*)d_ws + (size_t)2 * CLOUD * 8);
    float* part = aa + (size_t)2 * CLOUD;

    hipMemsetAsync(out, 0, sizeof(float), stream);   // d_out poisoned 0xAA

    prep_kernel<<<(2 * CLOUD) / 256, 256, 0, stream>>>(a1, a2, h4, aa);

    dim3 grid(NB, NP / 512, 2 * YSPL);   // 16 x 8 x 8 = 1024 blocks (4 waves)
    mfma_kernel<<<grid, 256, 0, stream>>>(h4, aa, part);

    reduce_kernel<<<(2 * CLOUD) / 1024, 1024, 0, stream>>>(part, aa, out);
}